// Round 5
// baseline (441.137 us; speedup 1.0000x reference)
//
#include <hip/hip_runtime.h>
#include <hip/hip_bf16.h>

// Problem constants
#define BB 4
#define LL 2048
#define SS 2048
#define EE 1024
#define HH 16
#define DD 64
#define MM (BB * LL)   // 8192 rows for all projections
#define LOG2E 1.44269504088896340736f

typedef unsigned short u16;
typedef u16   u16x4  __attribute__((ext_vector_type(4)));
typedef u16   u16x8  __attribute__((ext_vector_type(8)));
typedef float f32x4  __attribute__((ext_vector_type(4)));
typedef __bf16 bf16x4 __attribute__((ext_vector_type(4)));
typedef __bf16 bf16x8 __attribute__((ext_vector_type(8)));

__device__ __forceinline__ u16 f2bf(float x) {
    unsigned u = __float_as_uint(x);
    u += 0x7fffu + ((u >> 16) & 1u);       // RNE (inputs finite)
    return (u16)(u >> 16);
}
__device__ __forceinline__ float bf2f(u16 b) {
    return __uint_as_float(((unsigned)b) << 16);
}

// async global->LDS, 16B per lane; LDS dest is wave-uniform base + lane*16
__device__ __forceinline__ void gload16(const u16* g, u16* l) {
    __builtin_amdgcn_global_load_lds(
        (const __attribute__((address_space(1))) void*)g,
        (__attribute__((address_space(3))) void*)l, 16, 0, 0);
}

// ---------------------------------------------------------------------------
// Generic fp32 -> bf16 cast, 8 elems/thread (weights only)
__global__ __launch_bounds__(256) void f32_to_bf16_kernel(
    const float* __restrict__ in, u16* __restrict__ out)
{
    size_t idx = ((size_t)blockIdx.x * 256 + threadIdx.x) * 8;
    f32x4 a = *(const f32x4*)(in + idx);
    f32x4 b = *(const f32x4*)(in + idx + 4);
    u16x8 o;
#pragma unroll
    for (int j = 0; j < 4; j++) { o[j] = f2bf(a[j]); o[4 + j] = f2bf(b[j]); }
    *(u16x8*)(out + idx) = o;
}

// ---------------------------------------------------------------------------
// comb[l][s] = bf16((attn_bias + attn_mask) * log2(e))  -- log2 domain for exp2
__global__ __launch_bounds__(256) void combine_bias_kernel(
    const float* __restrict__ bias, const float* __restrict__ mask,
    u16* __restrict__ comb)
{
    int idx = (blockIdx.x * 256 + threadIdx.x) * 8;
    f32x4 a0 = *(const f32x4*)(bias + idx);
    f32x4 a1 = *(const f32x4*)(bias + idx + 4);
    f32x4 m0 = *(const f32x4*)(mask + idx);
    f32x4 m1 = *(const f32x4*)(mask + idx + 4);
    u16x8 o;
#pragma unroll
    for (int j = 0; j < 4; j++) {
        o[j]     = f2bf((a0[j] + m0[j]) * LOG2E);
        o[4 + j] = f2bf((a1[j] + m1[j]) * LOG2E);
    }
    *(u16x8*)(comb + idx) = o;
}

// ---------------------------------------------------------------------------
// C[m][n] = (sum_k A[m][k]*Bw[n][k] + bias[n]) * scale
// Fixed shape M=8192,N=1024,K=1024, grid 512 (1D), 128x128 tile, BK=64.
// ABF16=0: A fp32 reg-staged (fused cast); B double-buffered via
//   global_load_lds, staged AFTER barrier2 so loads land during compute
//   (no exposed drain at the next barrier).  LDS 50KB -> 3 blocks/CU.
// ABF16=1: A and B both dbuf gload -> single barrier per K-iter. 64KB LDS.
// XCD swizzle: each XCD gets 1 m-tile x all 8 n-tiles consecutively.
// VOUT=1: epilogue transposes via LDS and writes vt[b*16+h][d][s].
template <int ABF16, int OUTBF16, int VOUT>
__global__ __launch_bounds__(256, 2) void gemm_bt(
    const void* __restrict__ Ap, const u16* __restrict__ Bw,
    const float* __restrict__ bias, void* __restrict__ Cp,
    int M, int N, int K, float scale)
{
    // fp32 path: As 128x72 (18KB) + Bs dbuf 2x128x64 (32KB) = 50KB
    // bf16 path: As dbuf 32KB + Bs dbuf 32KB = 64KB
    __shared__ __align__(16) u16 SH[ABF16 ? (4 * 128 * 64) : (128 * 72 + 2 * 128 * 64)];
    constexpr int ASTR = ABF16 ? 64 : 72;
    u16* As  = SH;                                  // [dbuf][128*64] if ABF16
    u16* Bs  = SH + (ABF16 ? 2 * 128 * 64 : 128 * 72);
    u16* Tr  = SH;                                  // VOUT transpose buffer

    const int tid = threadIdx.x;
    const int lane = tid & 63, wave = tid >> 6;
    const int quad = lane >> 4, ln = lane & 15;
    const int wm = (wave & 1) * 64, wn = (wave >> 1) * 64;

    const int bid = blockIdx.x;
    const int vid = (bid & 7) * 8 + ((bid >> 3) & 7) + (bid >> 6) * 64;
    const int m0 = (vid >> 3) * 128, n0 = (vid & 7) * 128;

    const int r8 = lane >> 3, c8 = lane & 7;
    const float* Af = (const float*)Ap;
    const u16*   Ab = (const u16*)Ap + (size_t)m0 * K + c8 * 8;
    const u16*   Bg = Bw + (size_t)n0 * K + c8 * 8;

    f32x4 acc[4][4];
#pragma unroll
    for (int mt = 0; mt < 4; mt++)
#pragma unroll
        for (int nt = 0; nt < 4; nt++) acc[mt][nt] = (f32x4){0.f, 0.f, 0.f, 0.f};

    f32x4 apf[8];   // A prefetch regs (fp32 path)

    auto load_a = [&](int k0) {
        if (!ABF16) {
#pragma unroll
            for (int i = 0; i < 8; i++) {
                int chunk = tid + 256 * i, row = chunk >> 4, c = chunk & 15;
                apf[i] = *(const f32x4*)(Af + (size_t)(m0 + row) * K + k0 + c * 4);
            }
        }
    };
    auto stage_b = [&](int bu, int k0) {
#pragma unroll
        for (int i = 0; i < 4; i++) {
            int ch = i * 4 + wave;
            int row = ch * 8 + r8;
            gload16(Bg + (size_t)row * K + k0, &Bs[bu * (128 * 64) + ch * 512]);
        }
    };
    auto stage_a16 = [&](int bu, int k0) {
#pragma unroll
        for (int i = 0; i < 4; i++) {
            int ch = i * 4 + wave;
            int row = ch * 8 + r8;
            gload16(Ab + (size_t)row * K + k0, &As[bu * (128 * 64) + ch * 512]);
        }
    };

    load_a(0);
    stage_b(0, 0);
    if (ABF16) stage_a16(0, 0);

    int buf = 0;
    const int KT = K >> 6;
    for (int kt = 0; kt < KT; kt++) {
        const int k0 = kt << 6;
        __syncthreads();            // drains gloads for buf (issued >=1 compute ago)
        if (!ABF16) {               // A regs -> bf16 -> LDS (apf long landed)
#pragma unroll
            for (int i = 0; i < 8; i++) {
                int chunk = tid + 256 * i, row = chunk >> 4, c = chunk & 15;
                u16x4 o;
#pragma unroll
                for (int j = 0; j < 4; j++) o[j] = f2bf(apf[i][j]);
                *(u16x4*)(As + row * ASTR + c * 4) = o;
            }
            __syncthreads();        // lgkm drain only (cheap)
        }
        if (kt + 1 < KT) {          // prefetch next: lands during compute
            stage_b(buf ^ 1, k0 + 64);
            if (ABF16) stage_a16(buf ^ 1, k0 + 64);
            load_a(k0 + 64);
        }

        const u16* Ar = ABF16 ? &As[buf * (128 * 64)] : As;
        const u16* Br = &Bs[buf * (128 * 64)];
#pragma unroll
        for (int ks = 0; ks < 2; ks++) {
            bf16x8 af[4], bfg[4];
#pragma unroll
            for (int mt = 0; mt < 4; mt++)
                af[mt] = *(const bf16x8*)(&Ar[(wm + mt * 16 + ln) * ASTR + ks * 32 + quad * 8]);
#pragma unroll
            for (int nt = 0; nt < 4; nt++)
                bfg[nt] = *(const bf16x8*)(&Br[(wn + nt * 16 + ln) * 64 + ks * 32 + quad * 8]);
#pragma unroll
            for (int mt = 0; mt < 4; mt++)
#pragma unroll
                for (int nt = 0; nt < 4; nt++)
                    acc[mt][nt] = __builtin_amdgcn_mfma_f32_16x16x32_bf16(
                        af[mt], bfg[nt], acc[mt][nt], 0, 0, 0);
        }
        buf ^= 1;
    }

    if (VOUT) {
        __syncthreads();
#pragma unroll
        for (int nt = 0; nt < 4; nt++) {
            int nl = wn + nt * 16 + ln;
            float bn = bias[n0 + nl];
#pragma unroll
            for (int mt = 0; mt < 4; mt++)
#pragma unroll
                for (int r = 0; r < 4; r++) {
                    int ml = wm + mt * 16 + quad * 4 + r;
                    Tr[nl * 136 + ml] = f2bf(acc[mt][nt][r] + bn);   // scale==1
                }
        }
        __syncthreads();
        const int bq = m0 >> 11;               // batch index
        const int s0 = m0 & 2047;              // s offset within batch
#pragma unroll
        for (int i = 0; i < 8; i++) {
            int chunk = tid + 256 * i;         // 2048 = 128 rows x 16 chunks
            int row = chunk >> 4, c = chunk & 15;
            u16x8 v = *(const u16x8*)(Tr + row * 136 + c * 8);
            int n = n0 + row;
            int h = n >> 6, d = n & 63;
            *(u16x8*)(((u16*)Cp) + ((size_t)((bq * 16 + h) * 64 + d)) * SS + s0 + c * 8) = v;
        }
    } else {
#pragma unroll
        for (int nt = 0; nt < 4; nt++) {
            int n = n0 + wn + nt * 16 + ln;
            float bn = bias[n];
#pragma unroll
            for (int mt = 0; mt < 4; mt++) {
#pragma unroll
                for (int r = 0; r < 4; r++) {
                    int m = m0 + wm + mt * 16 + quad * 4 + r;
                    float val = (acc[mt][nt][r] + bn) * scale;
                    if (OUTBF16) ((u16*)Cp)[(size_t)m * N + n] = f2bf(val);
                    else         ((float*)Cp)[(size_t)m * N + n] = val;
                }
            }
        }
    }
}

// ---------------------------------------------------------------------------
// Attention, s-split QK: per block 128 q-rows of one (b,h); 4 waves.
// QK phase: each wave owns 2 of 8 s-subtiles x ALL 128 q (Q in 64 regs)
//   -> K LDS reads drop 16->4 per wave-iter (kernel was LDS-throughput-bound).
// P^T is cross-wave (wave writes its s-columns, all waves read) -> one extra
// barrier.  PV phase: wave owns q-rows [32w,32w+32) as before.
// lsum: per-qg partials, quad-reduce + cross-wave LDS reduce at the end.
__global__ __launch_bounds__(256, 2) void attn_kernel(
    const u16* __restrict__ qb,   // [B,L,E] bf16, pre-scaled (0.125*log2e)
    const u16* __restrict__ kb,   // [B,S,E] bf16
    const u16* __restrict__ vt,   // [B*H,64,S] bf16
    const u16* __restrict__ comb, // [L,S] bf16 (mask+bias)*log2e
    u16* __restrict__ attn)       // [B,L,E] bf16
{
    __shared__ __align__(16) u16 KPs[128 * 136];  // union: K tile (stride 72) / P^T (stride 136)
    __shared__ __align__(16) u16 Vs[64 * 136];    // V^T tile [d][s]; reused as f32 lsum scratch
    const int tid = threadIdx.x, lane = tid & 63, wave = tid >> 6;
    const int quad = lane >> 4, ln = lane & 15;

    const int bid = blockIdx.x;                   // XCD swizzle (bh-major vids)
    const int vid = (bid & 7) * 128 + (bid >> 3);
    const int bh = vid >> 4, b = bh >> 4, h = bh & 15;
    const int q0 = (vid & 15) * 128;
    const int qloc0 = wave * 32;                  // wave's q rows for PV

    // Q fragments for ALL 128 q-rows (8 groups of 16)
    bf16x8 qf[8][2];
#pragma unroll
    for (int qg = 0; qg < 8; qg++)
#pragma unroll
        for (int ks = 0; ks < 2; ks++)
            qf[qg][ks] = *(const bf16x8*)(qb + (size_t)(b * LL + q0 + qg * 16 + ln) * EE
                                          + h * 64 + ks * 32 + quad * 8);

    // bias base: row q = q0 + qg*16 + ln; col s = s0 + wave*32 + m*16 + quad*4
    const u16* cbase = comb + (size_t)(q0 + ln) * SS + wave * 32 + quad * 4;

    f32x4 o[4][2];
#pragma unroll
    for (int mt = 0; mt < 4; mt++) { o[mt][0] = (f32x4){0,0,0,0}; o[mt][1] = (f32x4){0,0,0,0}; }
    float ls[8];
#pragma unroll
    for (int qg = 0; qg < 8; qg++) ls[qg] = 0.f;

    u16x8 kreg[4], vreg[4];
    auto load_kv = [&](int s0) {
#pragma unroll
        for (int i = 0; i < 4; i++) {
            int chunk = tid + 256 * i, row = chunk >> 3, c = chunk & 7;   // 128 x 8
            kreg[i] = *(const u16x8*)(kb + (size_t)(b * SS + s0 + row) * EE + h * 64 + c * 8);
        }
#pragma unroll
        for (int i = 0; i < 4; i++) {
            int chunk = tid + 256 * i, row = chunk >> 4, c = chunk & 15;  // 64 x 16
            vreg[i] = *(const u16x8*)(vt + (size_t)(bh * 64 + row) * SS + s0 + c * 8);
        }
    };
    load_kv(0);

    for (int s0 = 0; s0 < SS; s0 += 128) {
        __syncthreads();                           // prev iter's P/V LDS reads done
#pragma unroll
        for (int i = 0; i < 4; i++) {              // K tile -> union (stride 72)
            int chunk = tid + 256 * i, row = chunk >> 3, c = chunk & 7;
            *(u16x8*)(KPs + row * 72 + c * 8) = kreg[i];
        }
#pragma unroll
        for (int i = 0; i < 4; i++) {              // V^T tile
            int chunk = tid + 256 * i, row = chunk >> 4, c = chunk & 15;
            *(u16x8*)(Vs + row * 136 + c * 8) = vreg[i];
        }
        // bias fragments for wave's s-range x all q
        u16x4 bfr[2][8];
#pragma unroll
        for (int m = 0; m < 2; m++)
#pragma unroll
            for (int qg = 0; qg < 8; qg++)
                bfr[m][qg] = *(const u16x4*)(cbase + (size_t)qg * 16 * SS + s0 + m * 16);
        __syncthreads();

        if (s0 + 128 < SS) load_kv(s0 + 128);      // prefetch next K/V into regs

        // S^T accumulator init with bias (log2 domain)
        f32x4 st[2][8];
#pragma unroll
        for (int m = 0; m < 2; m++)
#pragma unroll
            for (int qg = 0; qg < 8; qg++)
#pragma unroll
                for (int r = 0; r < 4; r++)
                    st[m][qg][r] = bf2f(bfr[m][qg][r]);

        // S^T[s][q] for wave's 2 s-subtiles, all q
        __builtin_amdgcn_s_setprio(1);
#pragma unroll
        for (int m = 0; m < 2; m++) {
            const int row = (wave * 2 + m) * 16 + ln;
            bf16x8 a0 = *(const bf16x8*)(KPs + row * 72 + quad * 8);
            bf16x8 a1 = *(const bf16x8*)(KPs + row * 72 + 32 + quad * 8);
#pragma unroll
            for (int qg = 0; qg < 8; qg++) {
                st[m][qg] = __builtin_amdgcn_mfma_f32_16x16x32_bf16(a0, qf[qg][0], st[m][qg], 0, 0, 0);
                st[m][qg] = __builtin_amdgcn_mfma_f32_16x16x32_bf16(a1, qf[qg][1], st[m][qg], 0, 0, 0);
            }
        }
        __builtin_amdgcn_s_setprio(0);

        // exp2 + bf16 pack
        bf16x4 p[2][8];
#pragma unroll
        for (int m = 0; m < 2; m++)
#pragma unroll
            for (int qg = 0; qg < 8; qg++)
#pragma unroll
                for (int r = 0; r < 4; r++) {
                    float e = __builtin_amdgcn_exp2f(st[m][qg][r]);
                    ls[qg] += e;
                    p[m][qg][r] = (__bf16)e;
                }

        __syncthreads();                           // all waves done reading K union

#pragma unroll
        for (int m = 0; m < 2; m++)                // P^T[q][s]: wave's s-columns
#pragma unroll
            for (int qg = 0; qg < 8; qg++)
                *(bf16x4*)(KPs + (qg * 16 + ln) * 136 + wave * 32 + m * 16 + quad * 4) = p[m][qg];

        __syncthreads();                           // P^T visible to all waves

        // O^T[d][q] += sum_s V^T[d][s] * P[s][q]   (wave's 32 q-rows)
#pragma unroll
        for (int ks = 0; ks < 4; ks++) {
            bf16x8 pf0 = *(const bf16x8*)(KPs + (qloc0 + ln) * 136 + ks * 32 + quad * 8);
            bf16x8 pf1 = *(const bf16x8*)(KPs + (qloc0 + 16 + ln) * 136 + ks * 32 + quad * 8);
            __builtin_amdgcn_s_setprio(1);
#pragma unroll
            for (int mt = 0; mt < 4; mt++) {
                bf16x8 a = *(const bf16x8*)(Vs + (mt * 16 + ln) * 136 + ks * 32 + quad * 8);
                o[mt][0] = __builtin_amdgcn_mfma_f32_16x16x32_bf16(a, pf0, o[mt][0], 0, 0, 0);
                o[mt][1] = __builtin_amdgcn_mfma_f32_16x16x32_bf16(a, pf1, o[mt][1], 0, 0, 0);
            }
            __builtin_amdgcn_s_setprio(0);
        }
    }

    // ---- lsum: quad-reduce, then cross-wave reduce via LDS scratch ----
#pragma unroll
    for (int qg = 0; qg < 8; qg++) {
        ls[qg] += __shfl_xor(ls[qg], 16);
        ls[qg] += __shfl_xor(ls[qg], 32);
    }
    __syncthreads();                               // last PV's Vs reads done
    float* lscr = (float*)Vs;                      // [wave][qg][ln] = 512 f32
    if (lane < 16) {
#pragma unroll
        for (int qg = 0; qg < 8; qg++)
            lscr[wave * 128 + qg * 16 + lane] = ls[qg];
    }
    __syncthreads();
    float lsum0 = 0.f, lsum1 = 0.f;
#pragma unroll
    for (int w = 0; w < 4; w++) {
        lsum0 += lscr[w * 128 + (2 * wave) * 16 + ln];
        lsum1 += lscr[w * 128 + (2 * wave + 1) * 16 + ln];
    }
    float inv0 = 1.f / lsum0, inv1 = 1.f / lsum1;

    // O^T -> LDS (wave-private rows) -> coalesced store
#pragma unroll
    for (int mt = 0; mt < 4; mt++) {
        bf16x4 p0, p1;
#pragma unroll
        for (int r = 0; r < 4; r++) {
            p0[r] = (__bf16)(o[mt][0][r] * inv0);
            p1[r] = (__bf16)(o[mt][1][r] * inv1);
        }
        *(bf16x4*)(KPs + (qloc0 + ln) * 136 + mt * 16 + quad * 4)      = p0;
        *(bf16x4*)(KPs + (qloc0 + 16 + ln) * 136 + mt * 16 + quad * 4) = p1;
    }
#pragma unroll
    for (int i = 0; i < 4; i++) {
        int j = lane + 64 * i;                     // 256 chunks over wave's 32 rows
        int r = j >> 3, c = j & 7;
        u16x8 v = *(const u16x8*)(KPs + (qloc0 + r) * 136 + c * 8);
        *(u16x8*)(attn + (size_t)(b * LL + q0 + qloc0 + r) * EE + h * 64 + c * 8) = v;
    }
}

// ---------------------------------------------------------------------------
extern "C" void kernel_launch(void* const* d_in, const int* in_sizes, int n_in,
                              void* d_out, int out_size, void* d_ws, size_t ws_size,
                              hipStream_t stream)
{
    (void)in_sizes; (void)n_in; (void)out_size; (void)ws_size;
    const float* query     = (const float*)d_in[0];
    const float* key       = (const float*)d_in[1];
    const float* value     = (const float*)d_in[2];
    const float* attn_bias = (const float*)d_in[3];
    const float* attn_mask = (const float*)d_in[4];
    const float* Wqkv      = (const float*)d_in[5];
    const float* bqkv      = (const float*)d_in[6];
    const float* Wo        = (const float*)d_in[7];
    const float* bo        = (const float*)d_in[8];
    float* out = (float*)d_out;

    // workspace layout (same offsets; v_bf slot unused)
    u16* wq_bf = (u16*)d_ws;                 // 3*EE*EE
    u16* wo_bf = wq_bf + 3 * EE * EE;        // EE*EE
    u16* comb  = wo_bf + EE * EE;            // LL*SS
    u16* q_bf  = comb + (size_t)LL * SS;     // MM*EE each:
    u16* k_bf  = q_bf + (size_t)MM * EE;
    u16* v_bf  = k_bf + (size_t)MM * EE;     // unused (layout stability)
    u16* vtr   = v_bf + (size_t)MM * EE;
    u16* attnb = vtr  + (size_t)MM * EE;

    f32_to_bf16_kernel<<<3 * EE * EE / 2048, 256, 0, stream>>>(Wqkv, wq_bf);
    f32_to_bf16_kernel<<<EE * EE / 2048, 256, 0, stream>>>(Wo, wo_bf);
    combine_bias_kernel<<<(LL * SS) / 2048, 256, 0, stream>>>(attn_bias, attn_mask, comb);

    // projections: fp32 A fused-cast, bf16 weights; q pre-scaled by 0.125*log2e
    gemm_bt<0, 1, 0><<<512, 256, 0, stream>>>(query, wq_bf,               bqkv,          q_bf, MM, EE, EE, 0.125f * LOG2E);
    gemm_bt<0, 1, 0><<<512, 256, 0, stream>>>(key,   wq_bf + EE * EE,     bqkv + EE,     k_bf, MM, EE, EE, 1.f);
    gemm_bt<0, 1, 1><<<512, 256, 0, stream>>>(value, wq_bf + 2 * EE * EE, bqkv + 2 * EE, vtr,  MM, EE, EE, 1.f);

    attn_kernel<<<1024, 256, 0, stream>>>(q_bf, k_bf, vtr, comb, attnb);

    gemm_bt<1, 0, 0><<<512, 256, 0, stream>>>(attnb, wo_bf, bo, out, MM, EE, EE, 1.f);
}